// Round 7
// baseline (241.584 us; speedup 1.0000x reference)
//
#include <hip/hip_runtime.h>

typedef unsigned short u16;
using bf16x8 = __attribute__((ext_vector_type(8))) __bf16;
using f32x4  = __attribute__((ext_vector_type(4))) float;
using f32x16 = __attribute__((ext_vector_type(16))) float;
using u16x8  = __attribute__((ext_vector_type(8))) unsigned short;
using u16x4  = __attribute__((ext_vector_type(4))) unsigned short;

#define SEQ   2048
#define HID   1024
#define NHEAD 16
#define HD    64
#define BATCH 2
#define NTOK  4096   // BATCH*SEQ

__device__ __forceinline__ u16 f2bf(float f) {
  unsigned u = __builtin_bit_cast(unsigned, f);
  u += 0x7fffu + ((u >> 16) & 1u);
  return (u16)(u >> 16);
}

__device__ __forceinline__ void gld_lds16(const void* g, void* l) {
  __builtin_amdgcn_global_load_lds(
      (__attribute__((address_space(1))) void*)(__UINTPTR_TYPE__)g,
      (__attribute__((address_space(3))) void*)l, 16, 0, 0);
}

__device__ __forceinline__ unsigned cvtpk(float lo, float hi) {
  unsigned r;
  asm("v_cvt_pk_bf16_f32 %0, %1, %2" : "=v"(r) : "v"(lo), "v"(hi));
  return r;
}
__device__ __forceinline__ void pswap(unsigned &a, unsigned &b) {
  asm volatile("v_permlane32_swap_b32 %0, %1" : "+v"(a), "+v"(b));
}

// ---------------- fp32 -> bf16 convert ----------------
__global__ __launch_bounds__(256) void cvt_kernel(const float* __restrict__ in,
                                                  u16* __restrict__ out) {
  int i = (blockIdx.x * 256 + threadIdx.x) * 4;
  float4 v = *reinterpret_cast<const float4*>(in + i);
  u16x4 o = { f2bf(v.x), f2bf(v.y), f2bf(v.z), f2bf(v.w) };
  *reinterpret_cast<u16x4*>(out + i) = o;
}

// ---------------- GEMM: C[M,N] = A[M,K] * B[N,K]^T ---------------- (unchanged)
template<bool BF16OUT>
__global__ __launch_bounds__(256) void gemm_bt(const u16* __restrict__ A,
                                               const u16* __restrict__ B,
                                               void* __restrict__ Cv,
                                               int M, int N, int K) {
  __shared__ u16 At[128 * 64];
  __shared__ u16 Bt[128 * 64];
  const int tid  = threadIdx.x;
  const int wave = tid >> 6;
  const int lane = tid & 63;
  const int g    = lane >> 4;
  const int r16  = lane & 15;
  const int wr   = wave >> 1;
  const int wc   = wave & 1;
  const int bm   = blockIdx.y;
  const int bn   = blockIdx.x;

  const u16* Ab = A + (size_t)bm * 128 * K;
  const u16* Bb = B + (size_t)bn * 128 * K;
  const int srow = lane >> 3;
  const int scol = (lane & 7) * 8;

  f32x4 acc[4][4] = {};

  for (int kt = 0; kt < K; kt += 64) {
#pragma unroll
    for (int c = 0; c < 4; ++c) {
      int seg = wave * 4 + c;
      gld_lds16(Ab + (size_t)(seg * 8 + srow) * K + kt + scol, &At[seg * 512]);
      gld_lds16(Bb + (size_t)(seg * 8 + srow) * K + kt + scol, &Bt[seg * 512]);
    }
    __syncthreads();
#pragma unroll
    for (int ko = 0; ko < 64; ko += 32) {
      bf16x8 af[4], bfr[4];
#pragma unroll
      for (int mi = 0; mi < 4; ++mi)
        af[mi] = *reinterpret_cast<const bf16x8*>(&At[(wr * 64 + mi * 16 + r16) * 64 + ko + g * 8]);
#pragma unroll
      for (int ni = 0; ni < 4; ++ni)
        bfr[ni] = *reinterpret_cast<const bf16x8*>(&Bt[(wc * 64 + ni * 16 + r16) * 64 + ko + g * 8]);
#pragma unroll
      for (int mi = 0; mi < 4; ++mi)
#pragma unroll
        for (int ni = 0; ni < 4; ++ni)
          acc[mi][ni] = __builtin_amdgcn_mfma_f32_16x16x32_bf16(af[mi], bfr[ni], acc[mi][ni], 0, 0, 0);
    }
    __syncthreads();
  }

#pragma unroll
  for (int mi = 0; mi < 4; ++mi)
#pragma unroll
    for (int ni = 0; ni < 4; ++ni) {
      int row0 = bm * 128 + wr * 64 + mi * 16 + g * 4;
      int col  = bn * 128 + wc * 64 + ni * 16 + r16;
#pragma unroll
      for (int r = 0; r < 4; ++r) {
        float v = acc[mi][ni][r];
        if (BF16OUT) ((u16*)Cv)[(size_t)(row0 + r) * N + col] = f2bf(v);
        else         ((float*)Cv)[(size_t)(row0 + r) * N + col] = v;
      }
    }
}

// ---------------- flash attention: swapped-QK^T, 32x32 MFMA ----------------
// 512 blocks (XCD-grouped heads), 4 waves x 32 q-rows (block = 128 q).
// S^T = mfma(K, Q): lane's col = q -> lane-local softmax (1 shfl hop).
// P^T -> PV B-operand via cvt_pk + permlane32_swap (no P LDS).
// K/Q fragments direct from global. V: round-4-verified swizzled LDS
// transpose, double-buffered, 1 barrier/tile.
__global__ __launch_bounds__(256, 2) void attn_kernel(const u16* __restrict__ qkv,
                                                      const float* __restrict__ mask,
                                                      u16* __restrict__ AO) {
  __shared__ u16 Vt[2][64 * 64];   // [d][key] swizzled, double-buffered

  const int tid  = threadIdx.x;
  const int w    = tid >> 6;
  const int lane = tid & 63;
  const int q31  = lane & 31;
  const int hi   = lane >> 5;

  // XCD-chunked remap: 16 heads of one (b,qt) share an XCD
  const int n  = blockIdx.x;           // 0..511
  const int x  = n & 7;
  const int s_ = n >> 3;               // 0..63
  const int h  = s_ & 15;
  const int t_ = ((s_ >> 4) << 3) + x; // 0..31
  const int b  = t_ >> 4;
  const int qt = t_ & 15;              // 128-row q tiles

  const size_t tokbase = (size_t)b * SEQ;
  const int qrow0 = qt * 128 + w * 32;
  const int q_lane = qrow0 + q31;

  // Q fragments: B-operand, lane: col=q31, k(d)-elems = 16s + 8*hi + j
  bf16x8 qf[4];
  {
    const u16* qb = qkv + ((tokbase + q_lane) * 3 + 0) * HID + h * HD + 8 * hi;
#pragma unroll
    for (int s = 0; s < 4; ++s)
      qf[s] = *reinterpret_cast<const bf16x8*>(qb + 16 * s);
  }
  const float* mrowp = mask + ((size_t)b * SEQ + q_lane) * SEQ;

  f32x16 oa0 = {}, oa1 = {};
  float mold = -3.0e38f, lsum = 0.f;

  const int vkey = tid >> 2;           // 0..63
  const int vd3  = tid & 3;

  // ---- prologue: K frags tile0, V regs tile0, stage Vt[0] ----
  bf16x8 kf[2][4];
#pragma unroll
  for (int t = 0; t < 2; ++t) {
    const u16* kb_ = qkv + ((tokbase + 0 + 32 * t + q31) * 3 + 1) * HID + h * HD + 8 * hi;
#pragma unroll
    for (int s = 0; s < 4; ++s)
      kf[t][s] = *reinterpret_cast<const bf16x8*>(kb_ + 16 * s);
  }
  u16x8 v0, v1;
  {
    const u16* vp = qkv + ((tokbase + 0 + vkey) * 3 + 2) * HID + h * HD + vd3 * 16;
    v0 = *reinterpret_cast<const u16x8*>(vp);
    v1 = *reinterpret_cast<const u16x8*>(vp + 8);
  }
#pragma unroll
  for (int j = 0; j < 16; ++j) {
    u16 val = (j < 8) ? (u16)v0[j] : (u16)v1[j - 8];
    int row = vd3 * 16 + j;
    int sV  = (vd3 + (j & 7)) & 7;
    Vt[0][row * 64 + (((vkey >> 3) ^ sV) << 3) + (vkey & 7)] = val;
  }
  __syncthreads();   // Vt[0] visible

#pragma unroll 1
  for (int kb = 0; kb < SEQ; kb += 64) {
    const int cur = (kb >> 6) & 1;
    const int nxt = cur ^ 1;
    const bool more = (kb + 64) < SEQ;

    // ---- S^T = K * Q^T (two 32-key subtiles) ----
    f32x16 sa0 = {}, sa1 = {};
#pragma unroll
    for (int s = 0; s < 4; ++s)
      sa0 = __builtin_amdgcn_mfma_f32_32x32x16_bf16(kf[0][s], qf[s], sa0, 0, 0, 0);
#pragma unroll
    for (int s = 0; s < 4; ++s)
      sa1 = __builtin_amdgcn_mfma_f32_32x32x16_bf16(kf[1][s], qf[s], sa1, 0, 0, 0);

    // ---- issue next tile's K frags + V regs (land during softmax/PV) ----
    if (more) {
#pragma unroll
      for (int t = 0; t < 2; ++t) {
        const u16* kb_ = qkv + ((tokbase + kb + 64 + 32 * t + q31) * 3 + 1) * HID + h * HD + 8 * hi;
#pragma unroll
        for (int s = 0; s < 4; ++s)
          kf[t][s] = *reinterpret_cast<const bf16x8*>(kb_ + 16 * s);
      }
      const u16* vp = qkv + ((tokbase + kb + 64 + vkey) * 3 + 2) * HID + h * HD + vd3 * 16;
      v0 = *reinterpret_cast<const u16x8*>(vp);
      v1 = *reinterpret_cast<const u16x8*>(vp + 8);
    }

    // ---- scale + mask (rows: (r&3)+8*(r>>2)+4*hi + 32*t) ----
#pragma unroll
    for (int t = 0; t < 2; ++t) {
      float4 m4[4];
#pragma unroll
      for (int a = 0; a < 4; ++a)
        m4[a] = *reinterpret_cast<const float4*>(mrowp + kb + 32 * t + 8 * a + 4 * hi);
      f32x16& sa = t ? sa1 : sa0;
#pragma unroll
      for (int r = 0; r < 16; ++r)
        sa[r] = sa[r] * 0.125f + reinterpret_cast<const float*>(&m4[r >> 2])[r & 3];
    }

    // ---- lane-local online softmax (q = q31 for both hi-halves) ----
    float mx = -3.0e38f;
#pragma unroll
    for (int r = 0; r < 16; ++r) mx = fmaxf(mx, sa0[r]);
#pragma unroll
    for (int r = 0; r < 16; ++r) mx = fmaxf(mx, sa1[r]);
    mx = fmaxf(mx, __shfl_xor(mx, 32));
    float mnew  = fmaxf(mold, mx);
    float alpha = __expf(mold - mnew);
    mold = mnew;
#pragma unroll
    for (int r = 0; r < 16; ++r) { oa0[r] *= alpha; oa1[r] *= alpha; }
    float ps = 0.f;
#pragma unroll
    for (int r = 0; r < 16; ++r) { float p = __expf(sa0[r] - mnew); sa0[r] = p; ps += p; }
#pragma unroll
    for (int r = 0; r < 16; ++r) { float p = __expf(sa1[r] - mnew); sa1[r] = p; ps += p; }
    ps += __shfl_xor(ps, 32);
    lsum = lsum * alpha + ps;

    // ---- PV: per 16-key chunk c: build P^T B-frag in regs, read V^T A-frag ----
#pragma unroll
    for (int c = 0; c < 4; ++c) {
      const int cl = c & 1;            // chunk within subtile
      const f32x16& sa = (c >> 1) ? sa1 : sa0;
      unsigned X0 = cvtpk(sa[8 * cl + 0], sa[8 * cl + 1]);
      unsigned X1 = cvtpk(sa[8 * cl + 2], sa[8 * cl + 3]);
      unsigned X2 = cvtpk(sa[8 * cl + 4], sa[8 * cl + 5]);
      unsigned X3 = cvtpk(sa[8 * cl + 6], sa[8 * cl + 7]);
      pswap(X0, X2);                   // X0 -> j0..1 rows, X2 -> j4..5 rows
      pswap(X1, X3);                   // X1 -> j2..3,     X3 -> j6..7
      union { unsigned u[4]; bf16x8 v; } pb;
      pb.u[0] = X0; pb.u[1] = X1; pb.u[2] = X2; pb.u[3] = X3;
#pragma unroll
      for (int dt = 0; dt < 2; ++dt) {
        int row  = dt * 32 + q31;
        int srow = ((row >> 4) + (row & 7)) & 7;
        bf16x8 va = *reinterpret_cast<const bf16x8*>(
            &Vt[cur][row * 64 + (((2 * c + hi) ^ srow) << 3)]);
        f32x16& oa = dt ? oa1 : oa0;
        oa = __builtin_amdgcn_mfma_f32_32x32x16_bf16(va, pb.v, oa, 0, 0, 0);
      }
    }

    // ---- stage next V tile (regs landed during softmax/PV) ----
    if (more) {
#pragma unroll
      for (int j = 0; j < 16; ++j) {
        u16 val = (j < 8) ? (u16)v0[j] : (u16)v1[j - 8];
        int row = vd3 * 16 + j;
        int sV  = (vd3 + (j & 7)) & 7;
        Vt[nxt][row * 64 + (((vkey >> 3) ^ sV) << 3) + (vkey & 7)] = val;
      }
    }
    __syncthreads();   // Vt[nxt] visible; all reads of Vt[cur] done
  }

  // ---- finalize: O^T rows d=(r&3)+8*(r>>2)+4*hi+32*dt, col q ----
  float inv_l = 1.0f / lsum;
  u16* ob = AO + (tokbase + q_lane) * HID + h * HD;
#pragma unroll
  for (int dt = 0; dt < 2; ++dt) {
    const f32x16& oa = dt ? oa1 : oa0;
#pragma unroll
    for (int a = 0; a < 4; ++a) {
      u16x4 pk_;
#pragma unroll
      for (int i = 0; i < 4; ++i) pk_[i] = f2bf(oa[4 * a + i] * inv_l);
      *reinterpret_cast<u16x4*>(ob + dt * 32 + 8 * a + 4 * hi) = pk_;
    }
  }
}

// ---------------- launcher ----------------
extern "C" void kernel_launch(void* const* d_in, const int* in_sizes, int n_in,
                              void* d_out, int out_size, void* d_ws, size_t ws_size,
                              hipStream_t stream) {
  (void)in_sizes; (void)n_in; (void)out_size; (void)ws_size;
  const float* hs   = (const float*)d_in[0];
  const float* mask = (const float*)d_in[1];
  const float* wqkv = (const float*)d_in[2];
  const float* wo   = (const float*)d_in[3];
  float* out = (float*)d_out;

  char* ws   = (char*)d_ws;
  u16* Xb    = (u16*)(ws);                        // 4096x1024  (8 MiB)
  u16* Wqkvb = (u16*)(ws + 8u  * 1024 * 1024);    // 3072x1024  (6 MiB)
  u16* Wob   = (u16*)(ws + 14u * 1024 * 1024);    // 1024x1024  (2 MiB)
  u16* QKVb  = (u16*)(ws + 16u * 1024 * 1024);    // 4096x3072  (24 MiB)
  u16* AOb   = (u16*)(ws + 40u * 1024 * 1024);    // 4096x1024  (8 MiB)

  cvt_kernel<<<4096, 256, 0, stream>>>(hs,   Xb);
  cvt_kernel<<<3072, 256, 0, stream>>>(wqkv, Wqkvb);
  cvt_kernel<<<1024, 256, 0, stream>>>(wo,   Wob);

  gemm_bt<true ><<<dim3(3072 / 128, 4096 / 128), 256, 0, stream>>>(Xb,  Wqkvb, QKVb, NTOK, 3072, HID);
  attn_kernel   <<<512, 256, 0, stream>>>(QKVb, mask, AOb);
  gemm_bt<false><<<dim3(1024 / 128, 4096 / 128), 256, 0, stream>>>(AOb, Wob,  out,  NTOK, 1024, HID);
}

// Round 8
// 222.861 us; speedup vs baseline: 1.0840x; 1.0840x over previous
//
#include <hip/hip_runtime.h>

typedef unsigned short u16;
using bf16x8 = __attribute__((ext_vector_type(8))) __bf16;
using f32x4  = __attribute__((ext_vector_type(4))) float;
using f32x16 = __attribute__((ext_vector_type(16))) float;
using u16x8  = __attribute__((ext_vector_type(8))) unsigned short;
using u16x4  = __attribute__((ext_vector_type(4))) unsigned short;

#define SEQ   2048
#define HID   1024
#define NHEAD 16
#define HD    64
#define BATCH 2
#define NTOK  4096   // BATCH*SEQ

__device__ __forceinline__ u16 f2bf(float f) {
  unsigned u = __builtin_bit_cast(unsigned, f);
  u += 0x7fffu + ((u >> 16) & 1u);
  return (u16)(u >> 16);
}

__device__ __forceinline__ void gld_lds16(const void* g, void* l) {
  __builtin_amdgcn_global_load_lds(
      (__attribute__((address_space(1))) void*)(__UINTPTR_TYPE__)g,
      (__attribute__((address_space(3))) void*)l, 16, 0, 0);
}

__device__ __forceinline__ unsigned cvtpk(float lo, float hi) {
  unsigned r;
  asm("v_cvt_pk_bf16_f32 %0, %1, %2" : "=v"(r) : "v"(lo), "v"(hi));
  return r;
}
__device__ __forceinline__ void pswap(unsigned &a, unsigned &b) {
  asm volatile("v_permlane32_swap_b32 %0, %1" : "+v"(a), "+v"(b));
}

// barrier that does NOT drain vmcnt: lane-private global prefetches stay in
// flight; lgkmcnt(0) makes this wave's ds_writes visible before the barrier.
__device__ __forceinline__ void lds_barrier() {
  __builtin_amdgcn_sched_barrier(0);
  asm volatile("s_waitcnt lgkmcnt(0)" ::: "memory");
  __builtin_amdgcn_s_barrier();
  __builtin_amdgcn_sched_barrier(0);
}

// ---------------- fp32 -> bf16 convert ----------------
__global__ __launch_bounds__(256) void cvt_kernel(const float* __restrict__ in,
                                                  u16* __restrict__ out) {
  int i = (blockIdx.x * 256 + threadIdx.x) * 4;
  float4 v = *reinterpret_cast<const float4*>(in + i);
  u16x4 o = { f2bf(v.x), f2bf(v.y), f2bf(v.z), f2bf(v.w) };
  *reinterpret_cast<u16x4*>(out + i) = o;
}

// ---------------- GEMM: C[M,N] = A[M,K] * B[N,K]^T ---------------- (unchanged)
template<bool BF16OUT>
__global__ __launch_bounds__(256) void gemm_bt(const u16* __restrict__ A,
                                               const u16* __restrict__ B,
                                               void* __restrict__ Cv,
                                               int M, int N, int K) {
  __shared__ u16 At[128 * 64];
  __shared__ u16 Bt[128 * 64];
  const int tid  = threadIdx.x;
  const int wave = tid >> 6;
  const int lane = tid & 63;
  const int g    = lane >> 4;
  const int r16  = lane & 15;
  const int wr   = wave >> 1;
  const int wc   = wave & 1;
  const int bm   = blockIdx.y;
  const int bn   = blockIdx.x;

  const u16* Ab = A + (size_t)bm * 128 * K;
  const u16* Bb = B + (size_t)bn * 128 * K;
  const int srow = lane >> 3;
  const int scol = (lane & 7) * 8;

  f32x4 acc[4][4] = {};

  for (int kt = 0; kt < K; kt += 64) {
#pragma unroll
    for (int c = 0; c < 4; ++c) {
      int seg = wave * 4 + c;
      gld_lds16(Ab + (size_t)(seg * 8 + srow) * K + kt + scol, &At[seg * 512]);
      gld_lds16(Bb + (size_t)(seg * 8 + srow) * K + kt + scol, &Bt[seg * 512]);
    }
    __syncthreads();
#pragma unroll
    for (int ko = 0; ko < 64; ko += 32) {
      bf16x8 af[4], bfr[4];
#pragma unroll
      for (int mi = 0; mi < 4; ++mi)
        af[mi] = *reinterpret_cast<const bf16x8*>(&At[(wr * 64 + mi * 16 + r16) * 64 + ko + g * 8]);
#pragma unroll
      for (int ni = 0; ni < 4; ++ni)
        bfr[ni] = *reinterpret_cast<const bf16x8*>(&Bt[(wc * 64 + ni * 16 + r16) * 64 + ko + g * 8]);
#pragma unroll
      for (int mi = 0; mi < 4; ++mi)
#pragma unroll
        for (int ni = 0; ni < 4; ++ni)
          acc[mi][ni] = __builtin_amdgcn_mfma_f32_16x16x32_bf16(af[mi], bfr[ni], acc[mi][ni], 0, 0, 0);
    }
    __syncthreads();
  }

#pragma unroll
  for (int mi = 0; mi < 4; ++mi)
#pragma unroll
    for (int ni = 0; ni < 4; ++ni) {
      int row0 = bm * 128 + wr * 64 + mi * 16 + g * 4;
      int col  = bn * 128 + wc * 64 + ni * 16 + r16;
#pragma unroll
      for (int r = 0; r < 4; ++r) {
        float v = acc[mi][ni][r];
        if (BF16OUT) ((u16*)Cv)[(size_t)(row0 + r) * N + col] = f2bf(v);
        else         ((float*)Cv)[(size_t)(row0 + r) * N + col] = v;
      }
    }
}

// ---------------- flash attention: swapped-QK^T, 32x32 MFMA ----------------
// 512 blocks (XCD-grouped heads), 4 waves x 32 q-rows (block = 128 q).
// r7 structure + (a) mask prefetched one tile ahead into regs,
// (b) raw lds_barrier (no vmcnt drain of lane-private prefetches).
__global__ __launch_bounds__(256, 2) void attn_kernel(const u16* __restrict__ qkv,
                                                      const float* __restrict__ mask,
                                                      u16* __restrict__ AO) {
  __shared__ u16 Vt[2][64 * 64];   // [d][key] swizzled, double-buffered

  const int tid  = threadIdx.x;
  const int w    = tid >> 6;
  const int lane = tid & 63;
  const int q31  = lane & 31;
  const int hi   = lane >> 5;

  const int n  = blockIdx.x;           // 0..511
  const int x  = n & 7;
  const int s_ = n >> 3;
  const int h  = s_ & 15;
  const int t_ = ((s_ >> 4) << 3) + x;
  const int b  = t_ >> 4;
  const int qt = t_ & 15;

  const size_t tokbase = (size_t)b * SEQ;
  const int qrow0 = qt * 128 + w * 32;
  const int q_lane = qrow0 + q31;

  bf16x8 qf[4];
  {
    const u16* qb = qkv + ((tokbase + q_lane) * 3 + 0) * HID + h * HD + 8 * hi;
#pragma unroll
    for (int s = 0; s < 4; ++s)
      qf[s] = *reinterpret_cast<const bf16x8*>(qb + 16 * s);
  }
  const float* mrowp = mask + ((size_t)b * SEQ + q_lane) * SEQ;

  f32x16 oa0 = {}, oa1 = {};
  float mold = -3.0e38f, lsum = 0.f;

  const int vkey = tid >> 2;
  const int vd3  = tid & 3;

  // ---- prologue: K frags, V regs, mask regs for tile 0; stage Vt[0] ----
  bf16x8 kf[2][4];
#pragma unroll
  for (int t = 0; t < 2; ++t) {
    const u16* kb_ = qkv + ((tokbase + 0 + 32 * t + q31) * 3 + 1) * HID + h * HD + 8 * hi;
#pragma unroll
    for (int s = 0; s < 4; ++s)
      kf[t][s] = *reinterpret_cast<const bf16x8*>(kb_ + 16 * s);
  }
  u16x8 v0, v1;
  {
    const u16* vp = qkv + ((tokbase + 0 + vkey) * 3 + 2) * HID + h * HD + vd3 * 16;
    v0 = *reinterpret_cast<const u16x8*>(vp);
    v1 = *reinterpret_cast<const u16x8*>(vp + 8);
  }
  float4 mreg[8];
#pragma unroll
  for (int t = 0; t < 2; ++t)
#pragma unroll
    for (int a = 0; a < 4; ++a)
      mreg[t * 4 + a] = *reinterpret_cast<const float4*>(mrowp + 0 + 32 * t + 8 * a + 4 * hi);
#pragma unroll
  for (int j = 0; j < 16; ++j) {
    u16 val = (j < 8) ? (u16)v0[j] : (u16)v1[j - 8];
    int row = vd3 * 16 + j;
    int sV  = (vd3 + (j & 7)) & 7;
    Vt[0][row * 64 + (((vkey >> 3) ^ sV) << 3) + (vkey & 7)] = val;
  }
  lds_barrier();   // Vt[0] visible

#pragma unroll 1
  for (int kb = 0; kb < SEQ; kb += 64) {
    const int cur = (kb >> 6) & 1;
    const int nxt = cur ^ 1;
    const bool more = (kb + 64) < SEQ;

    // ---- S^T = K * Q^T ----
    f32x16 sa0 = {}, sa1 = {};
#pragma unroll
    for (int s = 0; s < 4; ++s)
      sa0 = __builtin_amdgcn_mfma_f32_32x32x16_bf16(kf[0][s], qf[s], sa0, 0, 0, 0);
#pragma unroll
    for (int s = 0; s < 4; ++s)
      sa1 = __builtin_amdgcn_mfma_f32_32x32x16_bf16(kf[1][s], qf[s], sa1, 0, 0, 0);

    // ---- issue next tile's K frags + V regs ----
    if (more) {
#pragma unroll
      for (int t = 0; t < 2; ++t) {
        const u16* kb_ = qkv + ((tokbase + kb + 64 + 32 * t + q31) * 3 + 1) * HID + h * HD + 8 * hi;
#pragma unroll
        for (int s = 0; s < 4; ++s)
          kf[t][s] = *reinterpret_cast<const bf16x8*>(kb_ + 16 * s);
      }
      const u16* vp = qkv + ((tokbase + kb + 64 + vkey) * 3 + 2) * HID + h * HD + vd3 * 16;
      v0 = *reinterpret_cast<const u16x8*>(vp);
      v1 = *reinterpret_cast<const u16x8*>(vp + 8);
    }

    // ---- scale + mask from prefetched regs (rows: (r&3)+8*(r>>2)+4*hi+32*t) ----
#pragma unroll
    for (int t = 0; t < 2; ++t) {
      f32x16& sa = t ? sa1 : sa0;
#pragma unroll
      for (int r = 0; r < 16; ++r)
        sa[r] = sa[r] * 0.125f +
                reinterpret_cast<const float*>(&mreg[t * 4 + (r >> 2)])[r & 3];
    }

    // ---- prefetch next tile's mask (consumed next iteration) ----
    if (more) {
#pragma unroll
      for (int t = 0; t < 2; ++t)
#pragma unroll
        for (int a = 0; a < 4; ++a)
          mreg[t * 4 + a] = *reinterpret_cast<const float4*>(
              mrowp + kb + 64 + 32 * t + 8 * a + 4 * hi);
    }

    // ---- lane-local online softmax ----
    float mx = -3.0e38f;
#pragma unroll
    for (int r = 0; r < 16; ++r) mx = fmaxf(mx, sa0[r]);
#pragma unroll
    for (int r = 0; r < 16; ++r) mx = fmaxf(mx, sa1[r]);
    mx = fmaxf(mx, __shfl_xor(mx, 32));
    float mnew  = fmaxf(mold, mx);
    float alpha = __expf(mold - mnew);
    mold = mnew;
#pragma unroll
    for (int r = 0; r < 16; ++r) { oa0[r] *= alpha; oa1[r] *= alpha; }
    float ps = 0.f;
#pragma unroll
    for (int r = 0; r < 16; ++r) { float p = __expf(sa0[r] - mnew); sa0[r] = p; ps += p; }
#pragma unroll
    for (int r = 0; r < 16; ++r) { float p = __expf(sa1[r] - mnew); sa1[r] = p; ps += p; }
    ps += __shfl_xor(ps, 32);
    lsum = lsum * alpha + ps;

    // ---- PV ----
#pragma unroll
    for (int c = 0; c < 4; ++c) {
      const int cl = c & 1;
      const f32x16& sa = (c >> 1) ? sa1 : sa0;
      unsigned X0 = cvtpk(sa[8 * cl + 0], sa[8 * cl + 1]);
      unsigned X1 = cvtpk(sa[8 * cl + 2], sa[8 * cl + 3]);
      unsigned X2 = cvtpk(sa[8 * cl + 4], sa[8 * cl + 5]);
      unsigned X3 = cvtpk(sa[8 * cl + 6], sa[8 * cl + 7]);
      pswap(X0, X2);
      pswap(X1, X3);
      union { unsigned u[4]; bf16x8 v; } pb;
      pb.u[0] = X0; pb.u[1] = X1; pb.u[2] = X2; pb.u[3] = X3;
#pragma unroll
      for (int dt = 0; dt < 2; ++dt) {
        int row  = dt * 32 + q31;
        int srow = ((row >> 4) + (row & 7)) & 7;
        bf16x8 va = *reinterpret_cast<const bf16x8*>(
            &Vt[cur][row * 64 + (((2 * c + hi) ^ srow) << 3)]);
        f32x16& oa = dt ? oa1 : oa0;
        oa = __builtin_amdgcn_mfma_f32_32x32x16_bf16(va, pb.v, oa, 0, 0, 0);
      }
    }

    // ---- stage next V tile ----
    if (more) {
#pragma unroll
      for (int j = 0; j < 16; ++j) {
        u16 val = (j < 8) ? (u16)v0[j] : (u16)v1[j - 8];
        int row = vd3 * 16 + j;
        int sV  = (vd3 + (j & 7)) & 7;
        Vt[nxt][row * 64 + (((vkey >> 3) ^ sV) << 3) + (vkey & 7)] = val;
      }
    }
    lds_barrier();   // Vt[nxt] visible; reads of Vt[cur] done; no vmcnt drain
  }

  // ---- finalize ----
  float inv_l = 1.0f / lsum;
  u16* ob = AO + (tokbase + q_lane) * HID + h * HD;
#pragma unroll
  for (int dt = 0; dt < 2; ++dt) {
    const f32x16& oa = dt ? oa1 : oa0;
#pragma unroll
    for (int a = 0; a < 4; ++a) {
      u16x4 pk_;
#pragma unroll
      for (int i = 0; i < 4; ++i) pk_[i] = f2bf(oa[4 * a + i] * inv_l);
      *reinterpret_cast<u16x4*>(ob + dt * 32 + 8 * a + 4 * hi) = pk_;
    }
  }
}

// ---------------- launcher ----------------
extern "C" void kernel_launch(void* const* d_in, const int* in_sizes, int n_in,
                              void* d_out, int out_size, void* d_ws, size_t ws_size,
                              hipStream_t stream) {
  (void)in_sizes; (void)n_in; (void)out_size; (void)ws_size;
  const float* hs   = (const float*)d_in[0];
  const float* mask = (const float*)d_in[1];
  const float* wqkv = (const float*)d_in[2];
  const float* wo   = (const float*)d_in[3];
  float* out = (float*)d_out;

  char* ws   = (char*)d_ws;
  u16* Xb    = (u16*)(ws);                        // 4096x1024  (8 MiB)
  u16* Wqkvb = (u16*)(ws + 8u  * 1024 * 1024);    // 3072x1024  (6 MiB)
  u16* Wob   = (u16*)(ws + 14u * 1024 * 1024);    // 1024x1024  (2 MiB)
  u16* QKVb  = (u16*)(ws + 16u * 1024 * 1024);    // 4096x3072  (24 MiB)
  u16* AOb   = (u16*)(ws + 40u * 1024 * 1024);    // 4096x1024  (8 MiB)

  cvt_kernel<<<4096, 256, 0, stream>>>(hs,   Xb);
  cvt_kernel<<<3072, 256, 0, stream>>>(wqkv, Wqkvb);
  cvt_kernel<<<1024, 256, 0, stream>>>(wo,   Wob);

  gemm_bt<true ><<<dim3(3072 / 128, 4096 / 128), 256, 0, stream>>>(Xb,  Wqkvb, QKVb, NTOK, 3072, HID);
  attn_kernel   <<<512, 256, 0, stream>>>(QKVb, mask, AOb);
  gemm_bt<false><<<dim3(1024 / 128, 4096 / 128), 256, 0, stream>>>(AOb, Wob,  out,  NTOK, 1024, HID);
}